// Round 12
// baseline (102.641 us; speedup 1.0000x reference)
//
#include <hip/hip_runtime.h>

#define DIM 192
#define NB 8
#define NTOK 1024
#define HEADS 16
#define DH 64
#define INNER 1024
#define ROWS (NB * NTOK)  // 8192

typedef __bf16 bf16x8 __attribute__((ext_vector_type(8)));
typedef float f32x4 __attribute__((ext_vector_type(4)));
typedef float f32x16 __attribute__((ext_vector_type(16)));
typedef unsigned int u32x4 __attribute__((ext_vector_type(4)));

__device__ inline unsigned short f2bf(float f) {
    union { float f; unsigned u; } v; v.f = f;
    unsigned r = v.u + 0x7FFF + ((v.u >> 16) & 1);
    return (unsigned short)(r >> 16);
}

__device__ inline unsigned pk2(float a, float b) {
    __bf16 x = (__bf16)a, y = (__bf16)b;
    unsigned short ux = __builtin_bit_cast(unsigned short, x);
    unsigned short uy = __builtin_bit_cast(unsigned short, y);
    return (unsigned)ux | ((unsigned)uy << 16);
}

// async global->LDS, 16B per lane; dest must be wave-linear (base + lane*16)
__device__ inline void gl_lds16(const unsigned short* g, unsigned short* l) {
    __builtin_amdgcn_global_load_lds(
        (const __attribute__((address_space(1))) void*)g,
        (__attribute__((address_space(3))) void*)l, 16, 0, 0);
}

// fragment-major index for a [*][depth] bf16 operand consumed as 32x32x16
__device__ inline size_t fragIdx(int row, int k, int depth) {
    return ((size_t)(row >> 5) * ((size_t)depth * 4) +
            (size_t)(((k >> 4) * 2 + ((k >> 3) & 1)) * 32 + (row & 31))) * 8 + (k & 7);
}

// ---------------- fused preprocessing ----------------
__global__ __launch_bounds__(256) void k_pre(
    const float* __restrict__ x, const float* __restrict__ shift,
    const float* __restrict__ scale, const float* __restrict__ nw,
    const float* __restrict__ nb, const float* __restrict__ wqkv,
    const float* __restrict__ wout,
    unsigned short* __restrict__ hF, unsigned short* __restrict__ wF,
    unsigned short* __restrict__ woF) {
    int bid = blockIdx.x;
    if (bid < 2048) {
        int row = bid * 4 + (threadIdx.x >> 6);
        int lane = threadIdx.x & 63;
        const float* xr = x + row * DIM;
        float v0 = xr[lane], v1 = xr[lane + 64], v2 = xr[lane + 128];
        float s = v0 + v1 + v2;
        #pragma unroll
        for (int m = 1; m < 64; m <<= 1) s += __shfl_xor(s, m);
        float mean = s * (1.0f / DIM);
        float d0 = v0 - mean, d1 = v1 - mean, d2 = v2 - mean;
        float q = d0 * d0 + d1 * d1 + d2 * d2;
        #pragma unroll
        for (int m = 1; m < 64; m <<= 1) q += __shfl_xor(q, m);
        float rs = rsqrtf(q * (1.0f / DIM) + 1e-5f);
        int b = row >> 10;
        float vv[3] = {v0, v1, v2};
        #pragma unroll
        for (int i = 0; i < 3; i++) {
            int d = lane + 64 * i;
            float val = (vv[i] - mean) * rs * nw[d] + nb[d];
            val = val * (1.0f + scale[b * DIM + d]) + shift[b * DIM + d];
            hF[fragIdx(row, d, DIM)] = f2bf(val);
        }
    } else if (bid < 4352) {
        int idx = (bid - 2048) * 256 + threadIdx.x;  // < 192*3072
        int k = idx / 3072, c = idx % 3072;
        wF[fragIdx(c, k, DIM)] = f2bf(wqkv[idx]);
    } else {
        int idx = (bid - 4352) * 256 + threadIdx.x;  // < 1024*192
        int k = idx / 192, c = idx % 192;
        woF[fragIdx(c, k, INNER)] = f2bf(wout[idx]);
    }
}

// ---------------- QKV GEMM v3: fragment-major, LDS-free ----------------
// Q is pre-scaled by 0.125*log2(e) so k_attn's softmax is exp2(C) directly.
__global__ __launch_bounds__(256, 3) void k_qkv(
    const unsigned short* __restrict__ hF, const unsigned short* __restrict__ wF,
    unsigned short* __restrict__ qm, unsigned short* __restrict__ km,
    unsigned short* __restrict__ vtm) {
    const float QSC = 0.125f * 1.4426950408889634f;
    int tid = threadIdx.x;
    int wave = tid >> 6, lane = tid & 63;
    int l31 = lane & 31, hi = lane >> 5;
    int c0 = blockIdx.x * 64 + (wave >> 1) * 32;
    int typ = c0 >> 10;              // 0=Q 1=K 2=V
    int hd  = (c0 & 1023) >> 6;      // head
    int coff = c0 & 32;              // c-tile offset within head-panel

    const unsigned short* Ab = wF + (size_t)(c0 >> 5) * 768 * 8;
    bf16x8 af[12];
    #pragma unroll
    for (int kc = 0; kc < 12; kc++)
        af[kc] = *(const bf16x8*)(Ab + ((kc * 2 + hi) * 32 + l31) * 8);

    #pragma unroll
    for (int ns = 0; ns < 2; ns++) {
        int n0 = blockIdx.y * 128 + (wave & 1) * 64 + ns * 32;
        const unsigned short* Bb = hF + (size_t)(n0 >> 5) * 768 * 8;
        f32x16 acc;
        #pragma unroll
        for (int r = 0; r < 16; r++) acc[r] = 0.f;
        #pragma unroll
        for (int kc = 0; kc < 12; kc++) {
            bf16x8 bf = *(const bf16x8*)(Bb + ((kc * 2 + hi) * 32 + l31) * 8);
            acc = __builtin_amdgcn_mfma_f32_32x32x16_bf16(af[kc], bf, acc, 0, 0, 0);
        }
        int n = n0 + l31, bb = n >> 10, nm = n & 1023;
        if (typ < 2) {
            float sc = (typ == 0) ? QSC : 1.0f;
            unsigned short* base = (typ == 0 ? qm : km) +
                ((size_t)(bb * 16 + hd) * 1024 + nm) * 64;
            #pragma unroll
            for (int rg = 0; rg < 4; rg++) {
                uint2 val;
                val.x = pk2(acc[rg * 4 + 0] * sc, acc[rg * 4 + 1] * sc);
                val.y = pk2(acc[rg * 4 + 2] * sc, acc[rg * 4 + 3] * sc);
                *(uint2*)(base + coff + rg * 8 + hi * 4) = val;
            }
        } else {
            unsigned short* base = vtm + (size_t)(bb * 16 + hd) * 65536 + nm;
            #pragma unroll
            for (int r = 0; r < 16; r++) {
                int d = coff + (r & 3) + 8 * (r >> 2) + 4 * hi;
                base[(size_t)d * 1024] = f2bf(acc[r]);
            }
        }
    }
}

// ---------------- flash attention v8: v7 pipeline, 4-wave blocks for occupancy ----------------
// grid (128 bh, 8 qt) x 256 thr (4 waves) = 1024 blocks = 4/CU exactly
// (round-11 diagnosis: 512-block grid capped occupancy at ~1.3 blocks/CU).
// LDS 40KB x 4 blocks = 160KB = full CU capacity. XCD locality: all 8
// qt-blocks of a bh land on XCD bh%8; per-XCD KV working set = 4MB = L2.
__global__ __launch_bounds__(256, 4) void k_attn(
    const unsigned short* __restrict__ qm, const unsigned short* __restrict__ km,
    const unsigned short* __restrict__ vtm, unsigned short* __restrict__ attnF) {
    __shared__ __align__(128) unsigned short Kb[2][4096];
    __shared__ __align__(128) unsigned short Vb[3][4096];

    int tid = threadIdx.x;
    int wave = tid >> 6, lane = tid & 63;
    int l31 = lane & 31, hi = lane >> 5;
    int bh = blockIdx.x, qt = blockIdx.y;
    int qbase = qt * 128 + wave * 32;
    const unsigned short* Q = qm + (size_t)bh * NTOK * DH;
    const unsigned short* K = km + (size_t)bh * NTOK * DH;
    const unsigned short* VT = vtm + (size_t)bh * DH * NTOK;

    bf16x8 qf[4];
    #pragma unroll
    for (int c = 0; c < 4; c++)
        qf[c] = *(const bf16x8*)(Q + (qbase + l31) * DH + c * 16 + hi * 8);

    u32x4 ov; ov[0] = 0x3F803F80u; ov[1] = 0x3F803F80u; ov[2] = 0x3F803F80u; ov[3] = 0x3F803F80u;
    bf16x8 ones = __builtin_bit_cast(bf16x8, ov);

    f32x16 accO[2], accL;
    #pragma unroll
    for (int r = 0; r < 16; r++) { accO[0][r] = 0.f; accO[1][r] = 0.f; accL[r] = 0.f; }

    // 256 threads x 16B x 2 rounds = 8KB = one full tile per call
    auto stageK = [&](int b, int t) {
        #pragma unroll
        for (int r = 0; r < 2; r++) {
            int off = (tid + r * 256) * 16;
            int row = off >> 7, col = off & 127;
            int scol = col ^ ((row & 7) << 4);
            gl_lds16(K + (t * 64 + row) * DH + (scol >> 1),
                     (unsigned short*)((char*)Kb[b] + off));
        }
    };
    auto stageV = [&](int b, int t) {
        #pragma unroll
        for (int r = 0; r < 2; r++) {
            int off = (tid + r * 256) * 16;
            int row = off >> 7, col = off & 127;
            int scol = col ^ ((row & 7) << 4);
            gl_lds16(VT + (size_t)row * NTOK + t * 64 + (scol >> 1),
                     (unsigned short*)((char*)Vb[b] + off));
        }
    };
    auto ldK = [&](int b, int row, int col) -> bf16x8 {
        int scol = col ^ ((row & 7) << 4);
        return *(const bf16x8*)((const char*)Kb[b] + row * 128 + scol);
    };
    auto ldV = [&](int b, int row, int col) -> bf16x8 {
        int scol = col ^ ((row & 7) << 4);
        return *(const bf16x8*)((const char*)Vb[b] + row * 128 + scol);
    };
    auto packP = [&](const f32x16& P, bf16x8& w0, bf16x8& w1) {
        u32x4 A, B;
        {
            auto r0 = __builtin_amdgcn_permlane32_swap(pk2(P[0], P[1]), pk2(P[4], P[5]), false, false);
            auto r1 = __builtin_amdgcn_permlane32_swap(pk2(P[2], P[3]), pk2(P[6], P[7]), false, false);
            A[0] = r0[0]; A[1] = r1[0]; A[2] = r0[1]; A[3] = r1[1];
        }
        {
            auto r0 = __builtin_amdgcn_permlane32_swap(pk2(P[8], P[9]), pk2(P[12], P[13]), false, false);
            auto r1 = __builtin_amdgcn_permlane32_swap(pk2(P[10], P[11]), pk2(P[14], P[15]), false, false);
            B[0] = r0[0]; B[1] = r1[0]; B[2] = r0[1]; B[3] = r1[1];
        }
        w0 = __builtin_bit_cast(bf16x8, A);
        w1 = __builtin_bit_cast(bf16x8, B);
    };

    bf16x8 pw[4];

    stageK(0, 0); stageV(0, 0);
    __syncthreads();

    // ---- iter 0: QK(0), exp, pack, accL (no PV yet) ----
    stageK(1, 1); stageV(1, 1);
    {
        f32x16 C0, C1;
        #pragma unroll
        for (int r = 0; r < 16; r++) { C0[r] = 0.f; C1[r] = 0.f; }
        __builtin_amdgcn_s_setprio(1);
        #pragma unroll
        for (int c = 0; c < 4; c++) {
            bf16x8 kf = ldK(0, l31, c * 32 + hi * 16);
            C0 = __builtin_amdgcn_mfma_f32_32x32x16_bf16(kf, qf[c], C0, 0, 0, 0);
            bf16x8 kf2 = ldK(0, 32 + l31, c * 32 + hi * 16);
            C1 = __builtin_amdgcn_mfma_f32_32x32x16_bf16(kf2, qf[c], C1, 0, 0, 0);
        }
        __builtin_amdgcn_s_setprio(0);
        #pragma unroll
        for (int r = 0; r < 16; r++) {
            C0[r] = __builtin_amdgcn_exp2f(C0[r]);
            C1[r] = __builtin_amdgcn_exp2f(C1[r]);
        }
        packP(C0, pw[0], pw[1]);
        packP(C1, pw[2], pw[3]);
        #pragma unroll
        for (int kcc = 0; kcc < 4; kcc++)
            accL = __builtin_amdgcn_mfma_f32_32x32x16_bf16(ones, pw[kcc], accL, 0, 0, 0);
        __syncthreads();
    }

    // ---- steady state: QK(t) + PV(t-1) back-to-back, then exp/pack/accL ----
    for (int t = 1; t < 16; t++) {
        int kc = t & 1;
        int vp = (t - 1) % 3;
        if (t < 15) { stageK((t + 1) & 1, t + 1); stageV((t + 1) % 3, t + 1); }

        f32x16 C0, C1;
        #pragma unroll
        for (int r = 0; r < 16; r++) { C0[r] = 0.f; C1[r] = 0.f; }
        __builtin_amdgcn_s_setprio(1);
        #pragma unroll
        for (int c = 0; c < 4; c++) {
            bf16x8 kf = ldK(kc, l31, c * 32 + hi * 16);
            C0 = __builtin_amdgcn_mfma_f32_32x32x16_bf16(kf, qf[c], C0, 0, 0, 0);
            bf16x8 kf2 = ldK(kc, 32 + l31, c * 32 + hi * 16);
            C1 = __builtin_amdgcn_mfma_f32_32x32x16_bf16(kf2, qf[c], C1, 0, 0, 0);
        }
        // PV(t-1): independent of C(t); fills the MFMA pipe while exp waits
        #pragma unroll
        for (int dt = 0; dt < 2; dt++) {
            #pragma unroll
            for (int kcc = 0; kcc < 4; kcc++) {
                bf16x8 vf = ldV(vp, dt * 32 + l31, kcc * 32 + hi * 16);
                accO[dt] = __builtin_amdgcn_mfma_f32_32x32x16_bf16(vf, pw[kcc], accO[dt], 0, 0, 0);
            }
        }
        __builtin_amdgcn_s_setprio(0);

        #pragma unroll
        for (int r = 0; r < 16; r++) {
            C0[r] = __builtin_amdgcn_exp2f(C0[r]);
            C1[r] = __builtin_amdgcn_exp2f(C1[r]);
        }
        packP(C0, pw[0], pw[1]);
        packP(C1, pw[2], pw[3]);
        #pragma unroll
        for (int kcc = 0; kcc < 4; kcc++)
            accL = __builtin_amdgcn_mfma_f32_32x32x16_bf16(ones, pw[kcc], accL, 0, 0, 0);
        __syncthreads();
    }

    // ---- epilogue: PV(15); V(15) lives in Vb[15%3 == 0]; accL(15) done in-loop ----
    __builtin_amdgcn_s_setprio(1);
    #pragma unroll
    for (int dt = 0; dt < 2; dt++) {
        #pragma unroll
        for (int kcc = 0; kcc < 4; kcc++) {
            bf16x8 vf = ldV(0, dt * 32 + l31, kcc * 32 + hi * 16);
            accO[dt] = __builtin_amdgcn_mfma_f32_32x32x16_bf16(vf, pw[kcc], accO[dt], 0, 0, 0);
        }
    }
    __builtin_amdgcn_s_setprio(0);

    // l = accL[0] (every C/D row of mfma(ones,P^T) holds l(q=l31))
    float inv = 1.0f / accL[0];
    int b = bh >> 4, hd = bh & 15;
    int rowblk = b * 32 + qt * 4 + wave;  // (b*1024 + n) >> 5
    #pragma unroll
    for (int dt = 0; dt < 2; dt++)
        #pragma unroll
        for (int rq = 0; rq < 4; rq++) {
            int g = (hd * 4 + dt * 2 + (rq >> 1)) * 2 + (rq & 1);
            uint2 val;
            val.x = pk2(accO[dt][rq * 4 + 0] * inv, accO[dt][rq * 4 + 1] * inv);
            val.y = pk2(accO[dt][rq * 4 + 2] * inv, accO[dt][rq * 4 + 3] * inv);
            *(uint2*)((char*)attnF + ((size_t)rowblk * 4096 + g * 32 + l31) * 16 + hi * 8) = val;
        }
}

// ---------------- out projection v2: fragment-major, LDS-free ----------------
__global__ __launch_bounds__(256, 2) void k_out(
    const unsigned short* __restrict__ attnF, const unsigned short* __restrict__ woF,
    const float* __restrict__ bias, float* __restrict__ out) {
    int wave = threadIdx.x >> 6, lane = threadIdx.x & 63;
    int l31 = lane & 31, hi = lane >> 5;
    int W = blockIdx.x * 4 + wave;   // 0..1535
    int nb = W / 6, cb = W % 6;      // 256 n-blocks x 6 c-blocks
    const unsigned short* A = attnF + (size_t)nb * 4096 * 8;
    const unsigned short* B = woF + (size_t)cb * 4096 * 8;

    f32x16 acc;
    #pragma unroll
    for (int r = 0; r < 16; r++) acc[r] = 0.f;
    #pragma unroll 16
    for (int kc = 0; kc < 64; kc++) {
        bf16x8 a = *(const bf16x8*)(A + ((kc * 2 + hi) * 32 + l31) * 8);
        bf16x8 b = *(const bf16x8*)(B + ((kc * 2 + hi) * 32 + l31) * 8);
        acc = __builtin_amdgcn_mfma_f32_32x32x16_bf16(a, b, acc, 0, 0, 0);
    }
    float bi = bias[cb * 32 + l31];
    #pragma unroll
    for (int r = 0; r < 16; r++) {
        int n = nb * 32 + (r & 3) + 8 * (r >> 2) + 4 * hi;
        out[(size_t)n * DIM + cb * 32 + l31] = acc[r] + bi;
    }
}

extern "C" void kernel_launch(void* const* d_in, const int* in_sizes, int n_in,
                              void* d_out, int out_size, void* d_ws, size_t ws_size,
                              hipStream_t stream) {
    const float* x     = (const float*)d_in[0];
    const float* shift = (const float*)d_in[1];
    const float* scale = (const float*)d_in[2];
    const float* nw    = (const float*)d_in[3];
    const float* nbv   = (const float*)d_in[4];
    const float* wqkv  = (const float*)d_in[5];
    const float* wout  = (const float*)d_in[6];
    const float* bout  = (const float*)d_in[7];
    float* out = (float*)d_out;

    char* ws = (char*)d_ws;
    unsigned short* hF    = (unsigned short*)(ws + 0);
    unsigned short* wF    = (unsigned short*)(ws + 3145728);
    unsigned short* woF   = (unsigned short*)(ws + 3145728 + 1179648);
    unsigned short* qm    = (unsigned short*)(ws + 4718592);
    unsigned short* km    = (unsigned short*)(ws + 4718592 + 16777216);
    unsigned short* vtm   = (unsigned short*)(ws + 4718592 + 2 * 16777216);
    unsigned short* attnF = (unsigned short*)(ws + 4718592 + 3 * 16777216);

    k_pre<<<dim3(5120), dim3(256), 0, stream>>>(x, shift, scale, nw, nbv, wqkv, wout, hF, wF, woF);
    k_qkv<<<dim3(48, 64), dim3(256), 0, stream>>>(hF, wF, qm, km, vtm);
    k_attn<<<dim3(128, 8), dim3(256), 0, stream>>>(qm, km, vtm, attnF);
    k_out<<<dim3(384), dim3(256), 0, stream>>>(attnF, woF, bout, out);
}

// Round 13
// 101.820 us; speedup vs baseline: 1.0081x; 1.0081x over previous
//
#include <hip/hip_runtime.h>

#define DIM 192
#define NB 8
#define NTOK 1024
#define HEADS 16
#define DH 64
#define INNER 1024
#define ROWS (NB * NTOK)  // 8192

typedef __bf16 bf16x8 __attribute__((ext_vector_type(8)));
typedef float f32x4 __attribute__((ext_vector_type(4)));
typedef float f32x16 __attribute__((ext_vector_type(16)));
typedef unsigned int u32x4 __attribute__((ext_vector_type(4)));

__device__ inline unsigned short f2bf(float f) {
    union { float f; unsigned u; } v; v.f = f;
    unsigned r = v.u + 0x7FFF + ((v.u >> 16) & 1);
    return (unsigned short)(r >> 16);
}

__device__ inline unsigned pk2(float a, float b) {
    __bf16 x = (__bf16)a, y = (__bf16)b;
    unsigned short ux = __builtin_bit_cast(unsigned short, x);
    unsigned short uy = __builtin_bit_cast(unsigned short, y);
    return (unsigned)ux | ((unsigned)uy << 16);
}

// async global->LDS, 16B per lane; dest must be wave-linear (base + lane*16)
__device__ inline void gl_lds16(const unsigned short* g, unsigned short* l) {
    __builtin_amdgcn_global_load_lds(
        (const __attribute__((address_space(1))) void*)g,
        (__attribute__((address_space(3))) void*)l, 16, 0, 0);
}

// fragment-major index for a [*][depth] bf16 operand consumed as 32x32x16
__device__ inline size_t fragIdx(int row, int k, int depth) {
    return ((size_t)(row >> 5) * ((size_t)depth * 4) +
            (size_t)(((k >> 4) * 2 + ((k >> 3) & 1)) * 32 + (row & 31))) * 8 + (k & 7);
}

// ---------------- fused preprocessing ----------------
__global__ __launch_bounds__(256) void k_pre(
    const float* __restrict__ x, const float* __restrict__ shift,
    const float* __restrict__ scale, const float* __restrict__ nw,
    const float* __restrict__ nb, const float* __restrict__ wqkv,
    const float* __restrict__ wout,
    unsigned short* __restrict__ hF, unsigned short* __restrict__ wF,
    unsigned short* __restrict__ woF) {
    int bid = blockIdx.x;
    if (bid < 2048) {
        int row = bid * 4 + (threadIdx.x >> 6);
        int lane = threadIdx.x & 63;
        const float* xr = x + row * DIM;
        float v0 = xr[lane], v1 = xr[lane + 64], v2 = xr[lane + 128];
        float s = v0 + v1 + v2;
        #pragma unroll
        for (int m = 1; m < 64; m <<= 1) s += __shfl_xor(s, m);
        float mean = s * (1.0f / DIM);
        float d0 = v0 - mean, d1 = v1 - mean, d2 = v2 - mean;
        float q = d0 * d0 + d1 * d1 + d2 * d2;
        #pragma unroll
        for (int m = 1; m < 64; m <<= 1) q += __shfl_xor(q, m);
        float rs = rsqrtf(q * (1.0f / DIM) + 1e-5f);
        int b = row >> 10;
        float vv[3] = {v0, v1, v2};
        #pragma unroll
        for (int i = 0; i < 3; i++) {
            int d = lane + 64 * i;
            float val = (vv[i] - mean) * rs * nw[d] + nb[d];
            val = val * (1.0f + scale[b * DIM + d]) + shift[b * DIM + d];
            hF[fragIdx(row, d, DIM)] = f2bf(val);
        }
    } else if (bid < 4352) {
        int idx = (bid - 2048) * 256 + threadIdx.x;  // < 192*3072
        int k = idx / 3072, c = idx % 3072;
        wF[fragIdx(c, k, DIM)] = f2bf(wqkv[idx]);
    } else {
        int idx = (bid - 4352) * 256 + threadIdx.x;  // < 1024*192
        int k = idx / 192, c = idx % 192;
        woF[fragIdx(c, k, INNER)] = f2bf(wout[idx]);
    }
}

// ---------------- QKV GEMM v3: fragment-major, LDS-free ----------------
// Q is pre-scaled by 0.125*log2(e) so k_attn's softmax is exp2(C) directly.
__global__ __launch_bounds__(256, 3) void k_qkv(
    const unsigned short* __restrict__ hF, const unsigned short* __restrict__ wF,
    unsigned short* __restrict__ qm, unsigned short* __restrict__ km,
    unsigned short* __restrict__ vtm) {
    const float QSC = 0.125f * 1.4426950408889634f;
    int tid = threadIdx.x;
    int wave = tid >> 6, lane = tid & 63;
    int l31 = lane & 31, hi = lane >> 5;
    int c0 = blockIdx.x * 64 + (wave >> 1) * 32;
    int typ = c0 >> 10;              // 0=Q 1=K 2=V
    int hd  = (c0 & 1023) >> 6;      // head
    int coff = c0 & 32;              // c-tile offset within head-panel

    const unsigned short* Ab = wF + (size_t)(c0 >> 5) * 768 * 8;
    bf16x8 af[12];
    #pragma unroll
    for (int kc = 0; kc < 12; kc++)
        af[kc] = *(const bf16x8*)(Ab + ((kc * 2 + hi) * 32 + l31) * 8);

    #pragma unroll
    for (int ns = 0; ns < 2; ns++) {
        int n0 = blockIdx.y * 128 + (wave & 1) * 64 + ns * 32;
        const unsigned short* Bb = hF + (size_t)(n0 >> 5) * 768 * 8;
        f32x16 acc;
        #pragma unroll
        for (int r = 0; r < 16; r++) acc[r] = 0.f;
        #pragma unroll
        for (int kc = 0; kc < 12; kc++) {
            bf16x8 bf = *(const bf16x8*)(Bb + ((kc * 2 + hi) * 32 + l31) * 8);
            acc = __builtin_amdgcn_mfma_f32_32x32x16_bf16(af[kc], bf, acc, 0, 0, 0);
        }
        int n = n0 + l31, bb = n >> 10, nm = n & 1023;
        if (typ < 2) {
            float sc = (typ == 0) ? QSC : 1.0f;
            unsigned short* base = (typ == 0 ? qm : km) +
                ((size_t)(bb * 16 + hd) * 1024 + nm) * 64;
            #pragma unroll
            for (int rg = 0; rg < 4; rg++) {
                uint2 val;
                val.x = pk2(acc[rg * 4 + 0] * sc, acc[rg * 4 + 1] * sc);
                val.y = pk2(acc[rg * 4 + 2] * sc, acc[rg * 4 + 3] * sc);
                *(uint2*)(base + coff + rg * 8 + hi * 4) = val;
            }
        } else {
            unsigned short* base = vtm + (size_t)(bb * 16 + hd) * 65536 + nm;
            #pragma unroll
            for (int r = 0; r < 16; r++) {
                int d = coff + (r & 3) + 8 * (r >> 2) + 4 * hi;
                base[(size_t)d * 1024] = f2bf(acc[r]);
            }
        }
    }
}

// ---------------- flash attention v9: 64-q waves (2x LDS-read reuse) ----------------
// grid (128 bh, 8 qt) x 128 thr (2 waves). Wave owns 64 q-rows (two Q frag
// sets A/B); each ldK feeds 2 QK MFMAs, each ldV feeds 2 PV MFMAs ->
// LDS reads per FLOP halved (round-12 diagnosis: LDS read pipe ~30us of 50).
// Zero-max softmax; tree-summed per-half l (accL dropped to save VGPR).
__global__ __launch_bounds__(128, 2) void k_attn(
    const unsigned short* __restrict__ qm, const unsigned short* __restrict__ km,
    const unsigned short* __restrict__ vtm, unsigned short* __restrict__ attnF) {
    __shared__ __align__(128) unsigned short Kb[2][4096];
    __shared__ __align__(128) unsigned short Vb[3][4096];

    int tid = threadIdx.x;
    int wave = tid >> 6, lane = tid & 63;
    int l31 = lane & 31, hi = lane >> 5;
    int bh = blockIdx.x, qt = blockIdx.y;
    int qbase = qt * 128 + wave * 64;
    const unsigned short* Q = qm + (size_t)bh * NTOK * DH;
    const unsigned short* K = km + (size_t)bh * NTOK * DH;
    const unsigned short* VT = vtm + (size_t)bh * DH * NTOK;

    bf16x8 qfA[4], qfB[4];
    #pragma unroll
    for (int c = 0; c < 4; c++) {
        qfA[c] = *(const bf16x8*)(Q + (qbase + l31) * DH + c * 16 + hi * 8);
        qfB[c] = *(const bf16x8*)(Q + (qbase + 32 + l31) * DH + c * 16 + hi * 8);
    }

    float lA = 0.f, lB = 0.f;
    f32x16 accOA[2], accOB[2];
    #pragma unroll
    for (int r = 0; r < 16; r++) {
        accOA[0][r] = 0.f; accOA[1][r] = 0.f;
        accOB[0][r] = 0.f; accOB[1][r] = 0.f;
    }

    // 128 threads x 16B x 4 rounds = 8KB = one full tile per call
    auto stageK = [&](int b, int t) {
        #pragma unroll
        for (int r = 0; r < 4; r++) {
            int off = (tid + r * 128) * 16;
            int row = off >> 7, col = off & 127;
            int scol = col ^ ((row & 7) << 4);
            gl_lds16(K + (t * 64 + row) * DH + (scol >> 1),
                     (unsigned short*)((char*)Kb[b] + off));
        }
    };
    auto stageV = [&](int b, int t) {
        #pragma unroll
        for (int r = 0; r < 4; r++) {
            int off = (tid + r * 128) * 16;
            int row = off >> 7, col = off & 127;
            int scol = col ^ ((row & 7) << 4);
            gl_lds16(VT + (size_t)row * NTOK + t * 64 + (scol >> 1),
                     (unsigned short*)((char*)Vb[b] + off));
        }
    };
    auto ldK = [&](int b, int row, int col) -> bf16x8 {
        int scol = col ^ ((row & 7) << 4);
        return *(const bf16x8*)((const char*)Kb[b] + row * 128 + scol);
    };
    auto ldV = [&](int b, int row, int col) -> bf16x8 {
        int scol = col ^ ((row & 7) << 4);
        return *(const bf16x8*)((const char*)Vb[b] + row * 128 + scol);
    };
    auto packP = [&](const f32x16& P, bf16x8& w0, bf16x8& w1) {
        u32x4 A, B;
        {
            auto r0 = __builtin_amdgcn_permlane32_swap(pk2(P[0], P[1]), pk2(P[4], P[5]), false, false);
            auto r1 = __builtin_amdgcn_permlane32_swap(pk2(P[2], P[3]), pk2(P[6], P[7]), false, false);
            A[0] = r0[0]; A[1] = r1[0]; A[2] = r0[1]; A[3] = r1[1];
        }
        {
            auto r0 = __builtin_amdgcn_permlane32_swap(pk2(P[8], P[9]), pk2(P[12], P[13]), false, false);
            auto r1 = __builtin_amdgcn_permlane32_swap(pk2(P[10], P[11]), pk2(P[14], P[15]), false, false);
            B[0] = r0[0]; B[1] = r1[0]; B[2] = r0[1]; B[3] = r1[1];
        }
        w0 = __builtin_bit_cast(bf16x8, A);
        w1 = __builtin_bit_cast(bf16x8, B);
    };
    auto tsum = [](const f32x16& P) -> float {
        float s0 = (P[0] + P[1]) + (P[2] + P[3]);
        float s1 = (P[4] + P[5]) + (P[6] + P[7]);
        float s2 = (P[8] + P[9]) + (P[10] + P[11]);
        float s3 = (P[12] + P[13]) + (P[14] + P[15]);
        return (s0 + s1) + (s2 + s3);
    };

    bf16x8 pwA[4], pwB[4];

    stageK(0, 0); stageV(0, 0);
    __syncthreads();

    // ---- iter 0: QK(0), exp, pack (no PV yet) ----
    stageK(1, 1); stageV(1, 1);
    {
        f32x16 C0A, C0B, C1A, C1B;
        #pragma unroll
        for (int r = 0; r < 16; r++) { C0A[r] = 0.f; C0B[r] = 0.f; C1A[r] = 0.f; C1B[r] = 0.f; }
        __builtin_amdgcn_s_setprio(1);
        #pragma unroll
        for (int c = 0; c < 4; c++) {
            bf16x8 kf = ldK(0, l31, c * 32 + hi * 16);
            C0A = __builtin_amdgcn_mfma_f32_32x32x16_bf16(kf, qfA[c], C0A, 0, 0, 0);
            C0B = __builtin_amdgcn_mfma_f32_32x32x16_bf16(kf, qfB[c], C0B, 0, 0, 0);
            bf16x8 kf2 = ldK(0, 32 + l31, c * 32 + hi * 16);
            C1A = __builtin_amdgcn_mfma_f32_32x32x16_bf16(kf2, qfA[c], C1A, 0, 0, 0);
            C1B = __builtin_amdgcn_mfma_f32_32x32x16_bf16(kf2, qfB[c], C1B, 0, 0, 0);
        }
        __builtin_amdgcn_s_setprio(0);
        #pragma unroll
        for (int r = 0; r < 16; r++) {
            C0A[r] = __builtin_amdgcn_exp2f(C0A[r]);
            C0B[r] = __builtin_amdgcn_exp2f(C0B[r]);
            C1A[r] = __builtin_amdgcn_exp2f(C1A[r]);
            C1B[r] = __builtin_amdgcn_exp2f(C1B[r]);
        }
        lA += tsum(C0A) + tsum(C1A);
        lB += tsum(C0B) + tsum(C1B);
        packP(C0A, pwA[0], pwA[1]);
        packP(C1A, pwA[2], pwA[3]);
        packP(C0B, pwB[0], pwB[1]);
        packP(C1B, pwB[2], pwB[3]);
        __syncthreads();
    }

    // ---- steady state: QK(t) + PV(t-1) back-to-back, then exp/sum/pack ----
    for (int t = 1; t < 16; t++) {
        int kc = t & 1;
        int vp = (t - 1) % 3;
        if (t < 15) { stageK((t + 1) & 1, t + 1); stageV((t + 1) % 3, t + 1); }

        f32x16 C0A, C0B, C1A, C1B;
        #pragma unroll
        for (int r = 0; r < 16; r++) { C0A[r] = 0.f; C0B[r] = 0.f; C1A[r] = 0.f; C1B[r] = 0.f; }
        __builtin_amdgcn_s_setprio(1);
        #pragma unroll
        for (int c = 0; c < 4; c++) {
            bf16x8 kf = ldK(kc, l31, c * 32 + hi * 16);
            C0A = __builtin_amdgcn_mfma_f32_32x32x16_bf16(kf, qfA[c], C0A, 0, 0, 0);
            C0B = __builtin_amdgcn_mfma_f32_32x32x16_bf16(kf, qfB[c], C0B, 0, 0, 0);
            bf16x8 kf2 = ldK(kc, 32 + l31, c * 32 + hi * 16);
            C1A = __builtin_amdgcn_mfma_f32_32x32x16_bf16(kf2, qfA[c], C1A, 0, 0, 0);
            C1B = __builtin_amdgcn_mfma_f32_32x32x16_bf16(kf2, qfB[c], C1B, 0, 0, 0);
        }
        // PV(t-1): each ldV feeds both A and B accumulators
        #pragma unroll
        for (int dt = 0; dt < 2; dt++) {
            #pragma unroll
            for (int kcc = 0; kcc < 4; kcc++) {
                bf16x8 vf = ldV(vp, dt * 32 + l31, kcc * 32 + hi * 16);
                accOA[dt] = __builtin_amdgcn_mfma_f32_32x32x16_bf16(vf, pwA[kcc], accOA[dt], 0, 0, 0);
                accOB[dt] = __builtin_amdgcn_mfma_f32_32x32x16_bf16(vf, pwB[kcc], accOB[dt], 0, 0, 0);
            }
        }
        __builtin_amdgcn_s_setprio(0);

        #pragma unroll
        for (int r = 0; r < 16; r++) {
            C0A[r] = __builtin_amdgcn_exp2f(C0A[r]);
            C0B[r] = __builtin_amdgcn_exp2f(C0B[r]);
            C1A[r] = __builtin_amdgcn_exp2f(C1A[r]);
            C1B[r] = __builtin_amdgcn_exp2f(C1B[r]);
        }
        lA += tsum(C0A) + tsum(C1A);
        lB += tsum(C0B) + tsum(C1B);
        packP(C0A, pwA[0], pwA[1]);
        packP(C1A, pwA[2], pwA[3]);
        packP(C0B, pwB[0], pwB[1]);
        packP(C1B, pwB[2], pwB[3]);
        __syncthreads();
    }

    // ---- epilogue: PV(15); V(15) lives in Vb[15%3 == 0] ----
    __builtin_amdgcn_s_setprio(1);
    #pragma unroll
    for (int dt = 0; dt < 2; dt++) {
        #pragma unroll
        for (int kcc = 0; kcc < 4; kcc++) {
            bf16x8 vf = ldV(0, dt * 32 + l31, kcc * 32 + hi * 16);
            accOA[dt] = __builtin_amdgcn_mfma_f32_32x32x16_bf16(vf, pwA[kcc], accOA[dt], 0, 0, 0);
            accOB[dt] = __builtin_amdgcn_mfma_f32_32x32x16_bf16(vf, pwB[kcc], accOB[dt], 0, 0, 0);
        }
    }
    __builtin_amdgcn_s_setprio(0);

    float invA = 1.0f / (lA + __shfl_xor(lA, 32));
    float invB = 1.0f / (lB + __shfl_xor(lB, 32));
    int b = bh >> 4, hd = bh & 15;
    int rowblkA = b * 32 + qt * 4 + wave * 2;  // (b*1024 + qbase) >> 5
    #pragma unroll
    for (int half = 0; half < 2; half++) {
        const f32x16* accO = half ? accOB : accOA;
        float inv = half ? invB : invA;
        int rowblk = rowblkA + half;
        #pragma unroll
        for (int dt = 0; dt < 2; dt++)
            #pragma unroll
            for (int rq = 0; rq < 4; rq++) {
                int g = (hd * 4 + dt * 2 + (rq >> 1)) * 2 + (rq & 1);
                uint2 val;
                val.x = pk2(accO[dt][rq * 4 + 0] * inv, accO[dt][rq * 4 + 1] * inv);
                val.y = pk2(accO[dt][rq * 4 + 2] * inv, accO[dt][rq * 4 + 3] * inv);
                *(uint2*)((char*)attnF + ((size_t)rowblk * 4096 + g * 32 + l31) * 16 + hi * 8) = val;
            }
    }
}

// ---------------- out projection v2: fragment-major, LDS-free ----------------
__global__ __launch_bounds__(256, 2) void k_out(
    const unsigned short* __restrict__ attnF, const unsigned short* __restrict__ woF,
    const float* __restrict__ bias, float* __restrict__ out) {
    int wave = threadIdx.x >> 6, lane = threadIdx.x & 63;
    int l31 = lane & 31, hi = lane >> 5;
    int W = blockIdx.x * 4 + wave;   // 0..1535
    int nb = W / 6, cb = W % 6;      // 256 n-blocks x 6 c-blocks
    const unsigned short* A = attnF + (size_t)nb * 4096 * 8;
    const unsigned short* B = woF + (size_t)cb * 4096 * 8;

    f32x16 acc;
    #pragma unroll
    for (int r = 0; r < 16; r++) acc[r] = 0.f;
    #pragma unroll 16
    for (int kc = 0; kc < 64; kc++) {
        bf16x8 a = *(const bf16x8*)(A + ((kc * 2 + hi) * 32 + l31) * 8);
        bf16x8 b = *(const bf16x8*)(B + ((kc * 2 + hi) * 32 + l31) * 8);
        acc = __builtin_amdgcn_mfma_f32_32x32x16_bf16(a, b, acc, 0, 0, 0);
    }
    float bi = bias[cb * 32 + l31];
    #pragma unroll
    for (int r = 0; r < 16; r++) {
        int n = nb * 32 + (r & 3) + 8 * (r >> 2) + 4 * hi;
        out[(size_t)n * DIM + cb * 32 + l31] = acc[r] + bi;
    }
}

extern "C" void kernel_launch(void* const* d_in, const int* in_sizes, int n_in,
                              void* d_out, int out_size, void* d_ws, size_t ws_size,
                              hipStream_t stream) {
    const float* x     = (const float*)d_in[0];
    const float* shift = (const float*)d_in[1];
    const float* scale = (const float*)d_in[2];
    const float* nw    = (const float*)d_in[3];
    const float* nbv   = (const float*)d_in[4];
    const float* wqkv  = (const float*)d_in[5];
    const float* wout  = (const float*)d_in[6];
    const float* bout  = (const float*)d_in[7];
    float* out = (float*)d_out;

    char* ws = (char*)d_ws;
    unsigned short* hF    = (unsigned short*)(ws + 0);
    unsigned short* wF    = (unsigned short*)(ws + 3145728);
    unsigned short* woF   = (unsigned short*)(ws + 3145728 + 1179648);
    unsigned short* qm    = (unsigned short*)(ws + 4718592);
    unsigned short* km    = (unsigned short*)(ws + 4718592 + 16777216);
    unsigned short* vtm   = (unsigned short*)(ws + 4718592 + 2 * 16777216);
    unsigned short* attnF = (unsigned short*)(ws + 4718592 + 3 * 16777216);

    k_pre<<<dim3(5120), dim3(256), 0, stream>>>(x, shift, scale, nw, nbv, wqkv, wout, hF, wF, woF);
    k_qkv<<<dim3(48, 64), dim3(256), 0, stream>>>(hF, wF, qm, km, vtm);
    k_attn<<<dim3(128, 8), dim3(128), 0, stream>>>(qm, km, vtm, attnF);
    k_out<<<dim3(384), dim3(256), 0, stream>>>(attnF, woF, bout, out);
}

// Round 14
// 98.900 us; speedup vs baseline: 1.0378x; 1.0295x over previous
//
#include <hip/hip_runtime.h>

#define DIM 192
#define NB 8
#define NTOK 1024
#define HEADS 16
#define DH 64
#define INNER 1024
#define ROWS (NB * NTOK)  // 8192

typedef __bf16 bf16x8 __attribute__((ext_vector_type(8)));
typedef float f32x4 __attribute__((ext_vector_type(4)));
typedef float f32x16 __attribute__((ext_vector_type(16)));
typedef unsigned int u32x4 __attribute__((ext_vector_type(4)));

__device__ inline unsigned short f2bf(float f) {
    union { float f; unsigned u; } v; v.f = f;
    unsigned r = v.u + 0x7FFF + ((v.u >> 16) & 1);
    return (unsigned short)(r >> 16);
}

__device__ inline unsigned pk2(float a, float b) {
    __bf16 x = (__bf16)a, y = (__bf16)b;
    unsigned short ux = __builtin_bit_cast(unsigned short, x);
    unsigned short uy = __builtin_bit_cast(unsigned short, y);
    return (unsigned)ux | ((unsigned)uy << 16);
}

// async global->LDS, 16B per lane; dest must be wave-linear (base + lane*16)
__device__ inline void gl_lds16(const unsigned short* g, unsigned short* l) {
    __builtin_amdgcn_global_load_lds(
        (const __attribute__((address_space(1))) void*)g,
        (__attribute__((address_space(3))) void*)l, 16, 0, 0);
}

// fragment-major index for a [*][depth] bf16 operand consumed as 32x32x16
__device__ inline size_t fragIdx(int row, int k, int depth) {
    return ((size_t)(row >> 5) * ((size_t)depth * 4) +
            (size_t)(((k >> 4) * 2 + ((k >> 3) & 1)) * 32 + (row & 31))) * 8 + (k & 7);
}

// ---------------- fused preprocessing ----------------
__global__ __launch_bounds__(256) void k_pre(
    const float* __restrict__ x, const float* __restrict__ shift,
    const float* __restrict__ scale, const float* __restrict__ nw,
    const float* __restrict__ nb, const float* __restrict__ wqkv,
    const float* __restrict__ wout,
    unsigned short* __restrict__ hF, unsigned short* __restrict__ wF,
    unsigned short* __restrict__ woF) {
    int bid = blockIdx.x;
    if (bid < 2048) {
        int row = bid * 4 + (threadIdx.x >> 6);
        int lane = threadIdx.x & 63;
        const float* xr = x + row * DIM;
        float v0 = xr[lane], v1 = xr[lane + 64], v2 = xr[lane + 128];
        float s = v0 + v1 + v2;
        #pragma unroll
        for (int m = 1; m < 64; m <<= 1) s += __shfl_xor(s, m);
        float mean = s * (1.0f / DIM);
        float d0 = v0 - mean, d1 = v1 - mean, d2 = v2 - mean;
        float q = d0 * d0 + d1 * d1 + d2 * d2;
        #pragma unroll
        for (int m = 1; m < 64; m <<= 1) q += __shfl_xor(q, m);
        float rs = rsqrtf(q * (1.0f / DIM) + 1e-5f);
        int b = row >> 10;
        float vv[3] = {v0, v1, v2};
        #pragma unroll
        for (int i = 0; i < 3; i++) {
            int d = lane + 64 * i;
            float val = (vv[i] - mean) * rs * nw[d] + nb[d];
            val = val * (1.0f + scale[b * DIM + d]) + shift[b * DIM + d];
            hF[fragIdx(row, d, DIM)] = f2bf(val);
        }
    } else if (bid < 4352) {
        int idx = (bid - 2048) * 256 + threadIdx.x;  // < 192*3072
        int k = idx / 3072, c = idx % 3072;
        wF[fragIdx(c, k, DIM)] = f2bf(wqkv[idx]);
    } else {
        int idx = (bid - 4352) * 256 + threadIdx.x;  // < 1024*192
        int k = idx / 192, c = idx % 192;
        woF[fragIdx(c, k, INNER)] = f2bf(wout[idx]);
    }
}

// ---------------- QKV GEMM v4: fragment-major, LDS-free, split MFMA chains ----------------
// Q is pre-scaled by 0.125*log2(e) so k_attn's softmax is exp2(C) directly.
// 12-deep dependent MFMA chain split into 2x6 independent chains (acc0/acc1).
__global__ __launch_bounds__(256, 3) void k_qkv(
    const unsigned short* __restrict__ hF, const unsigned short* __restrict__ wF,
    unsigned short* __restrict__ qm, unsigned short* __restrict__ km,
    unsigned short* __restrict__ vtm) {
    const float QSC = 0.125f * 1.4426950408889634f;
    int tid = threadIdx.x;
    int wave = tid >> 6, lane = tid & 63;
    int l31 = lane & 31, hi = lane >> 5;
    int c0 = blockIdx.x * 64 + (wave >> 1) * 32;
    int typ = c0 >> 10;              // 0=Q 1=K 2=V
    int hd  = (c0 & 1023) >> 6;      // head
    int coff = c0 & 32;              // c-tile offset within head-panel

    const unsigned short* Ab = wF + (size_t)(c0 >> 5) * 768 * 8;
    bf16x8 af[12];
    #pragma unroll
    for (int kc = 0; kc < 12; kc++)
        af[kc] = *(const bf16x8*)(Ab + ((kc * 2 + hi) * 32 + l31) * 8);

    #pragma unroll
    for (int ns = 0; ns < 2; ns++) {
        int n0 = blockIdx.y * 128 + (wave & 1) * 64 + ns * 32;
        const unsigned short* Bb = hF + (size_t)(n0 >> 5) * 768 * 8;
        f32x16 acc0, acc1;
        #pragma unroll
        for (int r = 0; r < 16; r++) { acc0[r] = 0.f; acc1[r] = 0.f; }
        #pragma unroll
        for (int kc = 0; kc < 6; kc++) {
            bf16x8 bf0 = *(const bf16x8*)(Bb + (((2 * kc) * 2 + hi) * 32 + l31) * 8);
            bf16x8 bf1 = *(const bf16x8*)(Bb + (((2 * kc + 1) * 2 + hi) * 32 + l31) * 8);
            acc0 = __builtin_amdgcn_mfma_f32_32x32x16_bf16(af[2 * kc], bf0, acc0, 0, 0, 0);
            acc1 = __builtin_amdgcn_mfma_f32_32x32x16_bf16(af[2 * kc + 1], bf1, acc1, 0, 0, 0);
        }
        f32x16 acc;
        #pragma unroll
        for (int r = 0; r < 16; r++) acc[r] = acc0[r] + acc1[r];
        int n = n0 + l31, bb = n >> 10, nm = n & 1023;
        if (typ < 2) {
            float sc = (typ == 0) ? QSC : 1.0f;
            unsigned short* base = (typ == 0 ? qm : km) +
                ((size_t)(bb * 16 + hd) * 1024 + nm) * 64;
            #pragma unroll
            for (int rg = 0; rg < 4; rg++) {
                uint2 val;
                val.x = pk2(acc[rg * 4 + 0] * sc, acc[rg * 4 + 1] * sc);
                val.y = pk2(acc[rg * 4 + 2] * sc, acc[rg * 4 + 3] * sc);
                *(uint2*)(base + coff + rg * 8 + hi * 4) = val;
            }
        } else {
            unsigned short* base = vtm + (size_t)(bb * 16 + hd) * 65536 + nm;
            #pragma unroll
            for (int r = 0; r < 16; r++) {
                int d = coff + (r & 3) + 8 * (r >> 2) + 4 * hi;
                base[(size_t)d * 1024] = f2bf(acc[r]);
            }
        }
    }
}

// ---------------- flash attention v8 (round-12 version, best known 50.1us) ----------------
// grid (128 bh, 8 qt) x 256 thr (4 waves). v7 pipeline: zero-max softmax,
// QK(t)+PV(t-1) back-to-back, l-via-MFMA, __syncthreads dbuf.
__global__ __launch_bounds__(256, 4) void k_attn(
    const unsigned short* __restrict__ qm, const unsigned short* __restrict__ km,
    const unsigned short* __restrict__ vtm, unsigned short* __restrict__ attnF) {
    __shared__ __align__(128) unsigned short Kb[2][4096];
    __shared__ __align__(128) unsigned short Vb[3][4096];

    int tid = threadIdx.x;
    int wave = tid >> 6, lane = tid & 63;
    int l31 = lane & 31, hi = lane >> 5;
    int bh = blockIdx.x, qt = blockIdx.y;
    int qbase = qt * 128 + wave * 32;
    const unsigned short* Q = qm + (size_t)bh * NTOK * DH;
    const unsigned short* K = km + (size_t)bh * NTOK * DH;
    const unsigned short* VT = vtm + (size_t)bh * DH * NTOK;

    bf16x8 qf[4];
    #pragma unroll
    for (int c = 0; c < 4; c++)
        qf[c] = *(const bf16x8*)(Q + (qbase + l31) * DH + c * 16 + hi * 8);

    u32x4 ov; ov[0] = 0x3F803F80u; ov[1] = 0x3F803F80u; ov[2] = 0x3F803F80u; ov[3] = 0x3F803F80u;
    bf16x8 ones = __builtin_bit_cast(bf16x8, ov);

    f32x16 accO[2], accL;
    #pragma unroll
    for (int r = 0; r < 16; r++) { accO[0][r] = 0.f; accO[1][r] = 0.f; accL[r] = 0.f; }

    // 256 threads x 16B x 2 rounds = 8KB = one full tile per call
    auto stageK = [&](int b, int t) {
        #pragma unroll
        for (int r = 0; r < 2; r++) {
            int off = (tid + r * 256) * 16;
            int row = off >> 7, col = off & 127;
            int scol = col ^ ((row & 7) << 4);
            gl_lds16(K + (t * 64 + row) * DH + (scol >> 1),
                     (unsigned short*)((char*)Kb[b] + off));
        }
    };
    auto stageV = [&](int b, int t) {
        #pragma unroll
        for (int r = 0; r < 2; r++) {
            int off = (tid + r * 256) * 16;
            int row = off >> 7, col = off & 127;
            int scol = col ^ ((row & 7) << 4);
            gl_lds16(VT + (size_t)row * NTOK + t * 64 + (scol >> 1),
                     (unsigned short*)((char*)Vb[b] + off));
        }
    };
    auto ldK = [&](int b, int row, int col) -> bf16x8 {
        int scol = col ^ ((row & 7) << 4);
        return *(const bf16x8*)((const char*)Kb[b] + row * 128 + scol);
    };
    auto ldV = [&](int b, int row, int col) -> bf16x8 {
        int scol = col ^ ((row & 7) << 4);
        return *(const bf16x8*)((const char*)Vb[b] + row * 128 + scol);
    };
    auto packP = [&](const f32x16& P, bf16x8& w0, bf16x8& w1) {
        u32x4 A, B;
        {
            auto r0 = __builtin_amdgcn_permlane32_swap(pk2(P[0], P[1]), pk2(P[4], P[5]), false, false);
            auto r1 = __builtin_amdgcn_permlane32_swap(pk2(P[2], P[3]), pk2(P[6], P[7]), false, false);
            A[0] = r0[0]; A[1] = r1[0]; A[2] = r0[1]; A[3] = r1[1];
        }
        {
            auto r0 = __builtin_amdgcn_permlane32_swap(pk2(P[8], P[9]), pk2(P[12], P[13]), false, false);
            auto r1 = __builtin_amdgcn_permlane32_swap(pk2(P[10], P[11]), pk2(P[14], P[15]), false, false);
            B[0] = r0[0]; B[1] = r1[0]; B[2] = r0[1]; B[3] = r1[1];
        }
        w0 = __builtin_bit_cast(bf16x8, A);
        w1 = __builtin_bit_cast(bf16x8, B);
    };

    bf16x8 pw[4];

    stageK(0, 0); stageV(0, 0);
    __syncthreads();

    // ---- iter 0: QK(0), exp, pack, accL (no PV yet) ----
    stageK(1, 1); stageV(1, 1);
    {
        f32x16 C0, C1;
        #pragma unroll
        for (int r = 0; r < 16; r++) { C0[r] = 0.f; C1[r] = 0.f; }
        __builtin_amdgcn_s_setprio(1);
        #pragma unroll
        for (int c = 0; c < 4; c++) {
            bf16x8 kf = ldK(0, l31, c * 32 + hi * 16);
            C0 = __builtin_amdgcn_mfma_f32_32x32x16_bf16(kf, qf[c], C0, 0, 0, 0);
            bf16x8 kf2 = ldK(0, 32 + l31, c * 32 + hi * 16);
            C1 = __builtin_amdgcn_mfma_f32_32x32x16_bf16(kf2, qf[c], C1, 0, 0, 0);
        }
        __builtin_amdgcn_s_setprio(0);
        #pragma unroll
        for (int r = 0; r < 16; r++) {
            C0[r] = __builtin_amdgcn_exp2f(C0[r]);
            C1[r] = __builtin_amdgcn_exp2f(C1[r]);
        }
        packP(C0, pw[0], pw[1]);
        packP(C1, pw[2], pw[3]);
        #pragma unroll
        for (int kcc = 0; kcc < 4; kcc++)
            accL = __builtin_amdgcn_mfma_f32_32x32x16_bf16(ones, pw[kcc], accL, 0, 0, 0);
        __syncthreads();
    }

    // ---- steady state: QK(t) + PV(t-1) back-to-back, then exp/pack/accL ----
    for (int t = 1; t < 16; t++) {
        int kc = t & 1;
        int vp = (t - 1) % 3;
        if (t < 15) { stageK((t + 1) & 1, t + 1); stageV((t + 1) % 3, t + 1); }

        f32x16 C0, C1;
        #pragma unroll
        for (int r = 0; r < 16; r++) { C0[r] = 0.f; C1[r] = 0.f; }
        __builtin_amdgcn_s_setprio(1);
        #pragma unroll
        for (int c = 0; c < 4; c++) {
            bf16x8 kf = ldK(kc, l31, c * 32 + hi * 16);
            C0 = __builtin_amdgcn_mfma_f32_32x32x16_bf16(kf, qf[c], C0, 0, 0, 0);
            bf16x8 kf2 = ldK(kc, 32 + l31, c * 32 + hi * 16);
            C1 = __builtin_amdgcn_mfma_f32_32x32x16_bf16(kf2, qf[c], C1, 0, 0, 0);
        }
        // PV(t-1): independent of C(t); fills the MFMA pipe while exp waits
        #pragma unroll
        for (int dt = 0; dt < 2; dt++) {
            #pragma unroll
            for (int kcc = 0; kcc < 4; kcc++) {
                bf16x8 vf = ldV(vp, dt * 32 + l31, kcc * 32 + hi * 16);
                accO[dt] = __builtin_amdgcn_mfma_f32_32x32x16_bf16(vf, pw[kcc], accO[dt], 0, 0, 0);
            }
        }
        __builtin_amdgcn_s_setprio(0);

        #pragma unroll
        for (int r = 0; r < 16; r++) {
            C0[r] = __builtin_amdgcn_exp2f(C0[r]);
            C1[r] = __builtin_amdgcn_exp2f(C1[r]);
        }
        packP(C0, pw[0], pw[1]);
        packP(C1, pw[2], pw[3]);
        #pragma unroll
        for (int kcc = 0; kcc < 4; kcc++)
            accL = __builtin_amdgcn_mfma_f32_32x32x16_bf16(ones, pw[kcc], accL, 0, 0, 0);
        __syncthreads();
    }

    // ---- epilogue: PV(15); V(15) lives in Vb[15%3 == 0]; accL(15) done in-loop ----
    __builtin_amdgcn_s_setprio(1);
    #pragma unroll
    for (int dt = 0; dt < 2; dt++) {
        #pragma unroll
        for (int kcc = 0; kcc < 4; kcc++) {
            bf16x8 vf = ldV(0, dt * 32 + l31, kcc * 32 + hi * 16);
            accO[dt] = __builtin_amdgcn_mfma_f32_32x32x16_bf16(vf, pw[kcc], accO[dt], 0, 0, 0);
        }
    }
    __builtin_amdgcn_s_setprio(0);

    // l = accL[0] (every C/D row of mfma(ones,P^T) holds l(q=l31))
    float inv = 1.0f / accL[0];
    int b = bh >> 4, hd = bh & 15;
    int rowblk = b * 32 + qt * 4 + wave;  // (b*1024 + n) >> 5
    #pragma unroll
    for (int dt = 0; dt < 2; dt++)
        #pragma unroll
        for (int rq = 0; rq < 4; rq++) {
            int g = (hd * 4 + dt * 2 + (rq >> 1)) * 2 + (rq & 1);
            uint2 val;
            val.x = pk2(accO[dt][rq * 4 + 0] * inv, accO[dt][rq * 4 + 1] * inv);
            val.y = pk2(accO[dt][rq * 4 + 2] * inv, accO[dt][rq * 4 + 3] * inv);
            *(uint2*)((char*)attnF + ((size_t)rowblk * 4096 + g * 32 + l31) * 16 + hi * 8) = val;
        }
}

// ---------------- out projection v3: fragment-major, split MFMA chains ----------------
// 64-deep dependent MFMA chain split into 2x32 independent chains; merge + bias.
__global__ __launch_bounds__(256, 2) void k_out(
    const unsigned short* __restrict__ attnF, const unsigned short* __restrict__ woF,
    const float* __restrict__ bias, float* __restrict__ out) {
    int wave = threadIdx.x >> 6, lane = threadIdx.x & 63;
    int l31 = lane & 31, hi = lane >> 5;
    int W = blockIdx.x * 4 + wave;   // 0..1535
    int nb = W / 6, cb = W % 6;      // 256 n-blocks x 6 c-blocks
    const unsigned short* A = attnF + (size_t)nb * 4096 * 8;
    const unsigned short* B = woF + (size_t)cb * 4096 * 8;

    f32x16 acc0, acc1;
    #pragma unroll
    for (int r = 0; r < 16; r++) { acc0[r] = 0.f; acc1[r] = 0.f; }
    #pragma unroll 8
    for (int kc = 0; kc < 32; kc++) {
        bf16x8 a0 = *(const bf16x8*)(A + (((2 * kc) * 2 + hi) * 32 + l31) * 8);
        bf16x8 b0 = *(const bf16x8*)(B + (((2 * kc) * 2 + hi) * 32 + l31) * 8);
        bf16x8 a1 = *(const bf16x8*)(A + (((2 * kc + 1) * 2 + hi) * 32 + l31) * 8);
        bf16x8 b1 = *(const bf16x8*)(B + (((2 * kc + 1) * 2 + hi) * 32 + l31) * 8);
        acc0 = __builtin_amdgcn_mfma_f32_32x32x16_bf16(a0, b0, acc0, 0, 0, 0);
        acc1 = __builtin_amdgcn_mfma_f32_32x32x16_bf16(a1, b1, acc1, 0, 0, 0);
    }
    float bi = bias[cb * 32 + l31];
    #pragma unroll
    for (int r = 0; r < 16; r++) {
        int n = nb * 32 + (r & 3) + 8 * (r >> 2) + 4 * hi;
        out[(size_t)n * DIM + cb * 32 + l31] = acc0[r] + acc1[r] + bi;
    }
}

extern "C" void kernel_launch(void* const* d_in, const int* in_sizes, int n_in,
                              void* d_out, int out_size, void* d_ws, size_t ws_size,
                              hipStream_t stream) {
    const float* x     = (const float*)d_in[0];
    const float* shift = (const float*)d_in[1];
    const float* scale = (const float*)d_in[2];
    const float* nw    = (const float*)d_in[3];
    const float* nbv   = (const float*)d_in[4];
    const float* wqkv  = (const float*)d_in[5];
    const float* wout  = (const float*)d_in[6];
    const float* bout  = (const float*)d_in[7];
    float* out = (float*)d_out;

    char* ws = (char*)d_ws;
    unsigned short* hF    = (unsigned short*)(ws + 0);
    unsigned short* wF    = (unsigned short*)(ws + 3145728);
    unsigned short* woF   = (unsigned short*)(ws + 3145728 + 1179648);
    unsigned short* qm    = (unsigned short*)(ws + 4718592);
    unsigned short* km    = (unsigned short*)(ws + 4718592 + 16777216);
    unsigned short* vtm   = (unsigned short*)(ws + 4718592 + 2 * 16777216);
    unsigned short* attnF = (unsigned short*)(ws + 4718592 + 3 * 16777216);

    k_pre<<<dim3(5120), dim3(256), 0, stream>>>(x, shift, scale, nw, nbv, wqkv, wout, hF, wF, woF);
    k_qkv<<<dim3(48, 64), dim3(256), 0, stream>>>(hF, wF, qm, km, vtm);
    k_attn<<<dim3(128, 8), dim3(256), 0, stream>>>(qm, km, vtm, attnF);
    k_out<<<dim3(384), dim3(256), 0, stream>>>(attnF, woF, bout, out);
}

// Round 15
// 90.842 us; speedup vs baseline: 1.1299x; 1.0887x over previous
//
#include <hip/hip_runtime.h>

#define DIM 192
#define NB 8
#define NTOK 1024
#define HEADS 16
#define DH 64
#define INNER 1024
#define ROWS (NB * NTOK)  // 8192

typedef __bf16 bf16x8 __attribute__((ext_vector_type(8)));
typedef float f32x4 __attribute__((ext_vector_type(4)));
typedef float f32x16 __attribute__((ext_vector_type(16)));
typedef unsigned int u32x4 __attribute__((ext_vector_type(4)));

__device__ inline unsigned short f2bf(float f) {
    union { float f; unsigned u; } v; v.f = f;
    unsigned r = v.u + 0x7FFF + ((v.u >> 16) & 1);
    return (unsigned short)(r >> 16);
}

__device__ inline unsigned pk2(float a, float b) {
    __bf16 x = (__bf16)a, y = (__bf16)b;
    unsigned short ux = __builtin_bit_cast(unsigned short, x);
    unsigned short uy = __builtin_bit_cast(unsigned short, y);
    return (unsigned)ux | ((unsigned)uy << 16);
}

// fragment-major index for a [*][depth] bf16 operand consumed as 32x32x16
__device__ inline size_t fragIdx(int row, int k, int depth) {
    return ((size_t)(row >> 5) * ((size_t)depth * 4) +
            (size_t)(((k >> 4) * 2 + ((k >> 3) & 1)) * 32 + (row & 31))) * 8 + (k & 7);
}

// ---------------- fused preprocessing ----------------
__global__ __launch_bounds__(256) void k_pre(
    const float* __restrict__ x, const float* __restrict__ shift,
    const float* __restrict__ scale, const float* __restrict__ nw,
    const float* __restrict__ nb, const float* __restrict__ wqkv,
    const float* __restrict__ wout,
    unsigned short* __restrict__ hF, unsigned short* __restrict__ wF,
    unsigned short* __restrict__ woF) {
    int bid = blockIdx.x;
    if (bid < 2048) {
        int row = bid * 4 + (threadIdx.x >> 6);
        int lane = threadIdx.x & 63;
        const float* xr = x + row * DIM;
        float v0 = xr[lane], v1 = xr[lane + 64], v2 = xr[lane + 128];
        float s = v0 + v1 + v2;
        #pragma unroll
        for (int m = 1; m < 64; m <<= 1) s += __shfl_xor(s, m);
        float mean = s * (1.0f / DIM);
        float d0 = v0 - mean, d1 = v1 - mean, d2 = v2 - mean;
        float q = d0 * d0 + d1 * d1 + d2 * d2;
        #pragma unroll
        for (int m = 1; m < 64; m <<= 1) q += __shfl_xor(q, m);
        float rs = rsqrtf(q * (1.0f / DIM) + 1e-5f);
        int b = row >> 10;
        float vv[3] = {v0, v1, v2};
        #pragma unroll
        for (int i = 0; i < 3; i++) {
            int d = lane + 64 * i;
            float val = (vv[i] - mean) * rs * nw[d] + nb[d];
            val = val * (1.0f + scale[b * DIM + d]) + shift[b * DIM + d];
            hF[fragIdx(row, d, DIM)] = f2bf(val);
        }
    } else if (bid < 4352) {
        int idx = (bid - 2048) * 256 + threadIdx.x;  // < 192*3072
        int k = idx / 3072, c = idx % 3072;
        wF[fragIdx(c, k, DIM)] = f2bf(wqkv[idx]);
    } else {
        int idx = (bid - 4352) * 256 + threadIdx.x;  // < 1024*192
        int k = idx / 192, c = idx % 192;
        woF[fragIdx(c, k, INNER)] = f2bf(wout[idx]);
    }
}

// ---------------- QKV GEMM v5: fragment-major in AND out ----------------
// Q pre-scaled by 0.125*log2(e). Q/K/V^T all written in per-tile
// fragment-major granule order: per bh, tile t (64 tokens), granule
// g in [0,16), 32 lane-slots x 8 elems; addr(shorts) = (t*16+g)*256
// + slot*8 + sub*4, all uint2 stores fully coalesced.
// Q/K: g = (rowgrp_n*4 + (d>>4))*2 + ((d>>3)&1), slot = n&31.
// V^T: g = (drowgrp*4 + (n_t>>4))*2 + ((n_t>>3)&1), slot = d&31
//      (operands swapped: mfma(h, W) puts d on the D-lane).
__global__ __launch_bounds__(256, 3) void k_qkv(
    const unsigned short* __restrict__ hF, const unsigned short* __restrict__ wF,
    unsigned short* __restrict__ qmF, unsigned short* __restrict__ kmF,
    unsigned short* __restrict__ vtF) {
    const float QSC = 0.125f * 1.4426950408889634f;
    int tid = threadIdx.x;
    int wave = tid >> 6, lane = tid & 63;
    int l31 = lane & 31, hi = lane >> 5;
    int c0 = blockIdx.x * 64 + (wave >> 1) * 32;
    int typ = c0 >> 10;              // 0=Q 1=K 2=V
    int hd  = (c0 & 1023) >> 6;      // head
    int coff = c0 & 32;              // 32-channel tile within head panel

    const unsigned short* Ab = wF + (size_t)(c0 >> 5) * 768 * 8;
    bf16x8 af[12];
    #pragma unroll
    for (int kc = 0; kc < 12; kc++)
        af[kc] = *(const bf16x8*)(Ab + ((kc * 2 + hi) * 32 + l31) * 8);

    #pragma unroll
    for (int ns = 0; ns < 2; ns++) {
        int n0 = blockIdx.y * 128 + (wave & 1) * 64 + ns * 32;
        const unsigned short* Bb = hF + (size_t)(n0 >> 5) * 768 * 8;
        f32x16 acc0, acc1;
        #pragma unroll
        for (int r = 0; r < 16; r++) { acc0[r] = 0.f; acc1[r] = 0.f; }
        if (typ < 2) {
            #pragma unroll
            for (int kc = 0; kc < 6; kc++) {
                bf16x8 bf0 = *(const bf16x8*)(Bb + (((2 * kc) * 2 + hi) * 32 + l31) * 8);
                bf16x8 bf1 = *(const bf16x8*)(Bb + (((2 * kc + 1) * 2 + hi) * 32 + l31) * 8);
                acc0 = __builtin_amdgcn_mfma_f32_32x32x16_bf16(af[2 * kc], bf0, acc0, 0, 0, 0);
                acc1 = __builtin_amdgcn_mfma_f32_32x32x16_bf16(af[2 * kc + 1], bf1, acc1, 0, 0, 0);
            }
        } else {
            // V: swap operands so D-lane = channel (d), D-regs = token (n)
            #pragma unroll
            for (int kc = 0; kc < 6; kc++) {
                bf16x8 bf0 = *(const bf16x8*)(Bb + (((2 * kc) * 2 + hi) * 32 + l31) * 8);
                bf16x8 bf1 = *(const bf16x8*)(Bb + (((2 * kc + 1) * 2 + hi) * 32 + l31) * 8);
                acc0 = __builtin_amdgcn_mfma_f32_32x32x16_bf16(bf0, af[2 * kc], acc0, 0, 0, 0);
                acc1 = __builtin_amdgcn_mfma_f32_32x32x16_bf16(bf1, af[2 * kc + 1], acc1, 0, 0, 0);
            }
        }
        f32x16 acc;
        #pragma unroll
        for (int r = 0; r < 16; r++) acc[r] = acc0[r] + acc1[r];

        int bb = n0 >> 10, nm = n0 & 1023;
        int tt = nm >> 6;
        unsigned short* base;
        if (typ == 0) base = qmF + (size_t)(bb * 16 + hd) * 65536;
        else if (typ == 1) base = kmF + (size_t)(bb * 16 + hd) * 65536;
        else base = vtF + (size_t)(bb * 16 + hd) * 65536;

        if (typ < 2) {
            float sc = (typ == 0) ? QSC : 1.0f;
            int rowgrp = (nm >> 5) & 1;
            #pragma unroll
            for (int rg = 0; rg < 4; rg++) {
                int ob = coff + rg * 8;   // d-octet base
                int g = (rowgrp * 4 + (ob >> 4)) * 2 + ((ob >> 3) & 1);
                uint2 val;
                val.x = pk2(acc[rg * 4 + 0] * sc, acc[rg * 4 + 1] * sc);
                val.y = pk2(acc[rg * 4 + 2] * sc, acc[rg * 4 + 3] * sc);
                *(uint2*)(base + (tt * 16 + g) * 256 + l31 * 8 + hi * 4) = val;
            }
        } else {
            int drg = coff >> 5;
            #pragma unroll
            for (int rg = 0; rg < 4; rg++) {
                int nb2 = (nm & 32) + rg * 8;  // n-octet base within tile
                int g = (drg * 4 + (nb2 >> 4)) * 2 + ((nb2 >> 3) & 1);
                uint2 val;
                val.x = pk2(acc[rg * 4 + 0], acc[rg * 4 + 1]);
                val.y = pk2(acc[rg * 4 + 2], acc[rg * 4 + 3]);
                *(uint2*)(base + (tt * 16 + g) * 256 + l31 * 8 + hi * 4) = val;
            }
        }
    }
}

// ---------------- flash attention v10: LDS-FREE, fragment-major direct reads ----------------
// grid (128 bh, 8 qt) x 256 thr (4 waves). Wave owns 32 q-rows; KVBLK=64.
// All K/V/Q fragment loads are coalesced 16B/lane from L2 (fragment-major
// layout) -- no LDS, no barriers, no bank conflicts. Zero-max softmax;
// QK(t)+PV(t-1) register pipeline; l by tree-sum + one shfl.
__global__ __launch_bounds__(256, 3) void k_attn(
    const unsigned short* __restrict__ qmF, const unsigned short* __restrict__ kmF,
    const unsigned short* __restrict__ vtF, unsigned short* __restrict__ attnF) {
    int tid = threadIdx.x;
    int wave = tid >> 6, lane = tid & 63;
    int l31 = lane & 31, hi = lane >> 5;
    int bh = blockIdx.x, qt = blockIdx.y;
    int qbase = qt * 128 + wave * 32;
    const unsigned short* Qb = qmF + (size_t)bh * 65536;
    const unsigned short* Kb = kmF + (size_t)bh * 65536;
    const unsigned short* Vb = vtF + (size_t)bh * 65536;

    // Q fragments: tile tq, rowgrp rq, chunk c, half hi
    int tq = qbase >> 6, rq = (qbase >> 5) & 1;
    bf16x8 qf[4];
    #pragma unroll
    for (int c = 0; c < 4; c++)
        qf[c] = *(const bf16x8*)(Qb + (tq * 16 + (rq * 4 + c) * 2 + hi) * 256 + l31 * 8);

    float lsum = 0.f;
    f32x16 accO[2];
    #pragma unroll
    for (int r = 0; r < 16; r++) { accO[0][r] = 0.f; accO[1][r] = 0.f; }

    auto ldKf = [&](int t, int rowgrp, int c) -> bf16x8 {
        return *(const bf16x8*)(Kb + (t * 16 + (rowgrp * 4 + c) * 2 + hi) * 256 + l31 * 8);
    };
    auto ldVf = [&](int t, int dt, int nc) -> bf16x8 {
        return *(const bf16x8*)(Vb + (t * 16 + (dt * 4 + nc) * 2 + hi) * 256 + l31 * 8);
    };
    auto packP = [&](const f32x16& P, bf16x8& w0, bf16x8& w1) {
        u32x4 A, B;
        {
            auto r0 = __builtin_amdgcn_permlane32_swap(pk2(P[0], P[1]), pk2(P[4], P[5]), false, false);
            auto r1 = __builtin_amdgcn_permlane32_swap(pk2(P[2], P[3]), pk2(P[6], P[7]), false, false);
            A[0] = r0[0]; A[1] = r1[0]; A[2] = r0[1]; A[3] = r1[1];
        }
        {
            auto r0 = __builtin_amdgcn_permlane32_swap(pk2(P[8], P[9]), pk2(P[12], P[13]), false, false);
            auto r1 = __builtin_amdgcn_permlane32_swap(pk2(P[10], P[11]), pk2(P[14], P[15]), false, false);
            B[0] = r0[0]; B[1] = r1[0]; B[2] = r0[1]; B[3] = r1[1];
        }
        w0 = __builtin_bit_cast(bf16x8, A);
        w1 = __builtin_bit_cast(bf16x8, B);
    };
    auto tsum = [](const f32x16& P) -> float {
        float s0 = (P[0] + P[1]) + (P[2] + P[3]);
        float s1 = (P[4] + P[5]) + (P[6] + P[7]);
        float s2 = (P[8] + P[9]) + (P[10] + P[11]);
        float s3 = (P[12] + P[13]) + (P[14] + P[15]);
        return (s0 + s1) + (s2 + s3);
    };

    bf16x8 pw[4];

    // ---- iter 0: QK(0), exp, pack (no PV yet) ----
    {
        f32x16 C0, C1;
        #pragma unroll
        for (int r = 0; r < 16; r++) { C0[r] = 0.f; C1[r] = 0.f; }
        __builtin_amdgcn_s_setprio(1);
        #pragma unroll
        for (int c = 0; c < 4; c++) {
            C0 = __builtin_amdgcn_mfma_f32_32x32x16_bf16(ldKf(0, 0, c), qf[c], C0, 0, 0, 0);
            C1 = __builtin_amdgcn_mfma_f32_32x32x16_bf16(ldKf(0, 1, c), qf[c], C1, 0, 0, 0);
        }
        __builtin_amdgcn_s_setprio(0);
        #pragma unroll
        for (int r = 0; r < 16; r++) {
            C0[r] = __builtin_amdgcn_exp2f(C0[r]);
            C1[r] = __builtin_amdgcn_exp2f(C1[r]);
        }
        lsum += tsum(C0) + tsum(C1);
        packP(C0, pw[0], pw[1]);
        packP(C1, pw[2], pw[3]);
    }

    // ---- steady state: QK(t) + PV(t-1) back-to-back, then exp/sum/pack ----
    for (int t = 1; t < 16; t++) {
        f32x16 C0, C1;
        #pragma unroll
        for (int r = 0; r < 16; r++) { C0[r] = 0.f; C1[r] = 0.f; }
        __builtin_amdgcn_s_setprio(1);
        #pragma unroll
        for (int c = 0; c < 4; c++) {
            C0 = __builtin_amdgcn_mfma_f32_32x32x16_bf16(ldKf(t, 0, c), qf[c], C0, 0, 0, 0);
            C1 = __builtin_amdgcn_mfma_f32_32x32x16_bf16(ldKf(t, 1, c), qf[c], C1, 0, 0, 0);
        }
        #pragma unroll
        for (int dt = 0; dt < 2; dt++) {
            #pragma unroll
            for (int nc = 0; nc < 4; nc++) {
                accO[dt] = __builtin_amdgcn_mfma_f32_32x32x16_bf16(
                    ldVf(t - 1, dt, nc), pw[nc], accO[dt], 0, 0, 0);
            }
        }
        __builtin_amdgcn_s_setprio(0);

        #pragma unroll
        for (int r = 0; r < 16; r++) {
            C0[r] = __builtin_amdgcn_exp2f(C0[r]);
            C1[r] = __builtin_amdgcn_exp2f(C1[r]);
        }
        lsum += tsum(C0) + tsum(C1);
        packP(C0, pw[0], pw[1]);
        packP(C1, pw[2], pw[3]);
    }

    // ---- epilogue: PV(15) ----
    __builtin_amdgcn_s_setprio(1);
    #pragma unroll
    for (int dt = 0; dt < 2; dt++) {
        #pragma unroll
        for (int nc = 0; nc < 4; nc++) {
            accO[dt] = __builtin_amdgcn_mfma_f32_32x32x16_bf16(
                ldVf(15, dt, nc), pw[nc], accO[dt], 0, 0, 0);
        }
    }
    __builtin_amdgcn_s_setprio(0);

    float inv = 1.0f / (lsum + __shfl_xor(lsum, 32));
    int b = bh >> 4, hd = bh & 15;
    int rowblk = b * 32 + qt * 4 + wave;  // (b*1024 + qbase) >> 5
    #pragma unroll
    for (int dt = 0; dt < 2; dt++)
        #pragma unroll
        for (int rg = 0; rg < 4; rg++) {
            int g = (hd * 4 + dt * 2 + (rg >> 1)) * 2 + (rg & 1);
            uint2 val;
            val.x = pk2(accO[dt][rg * 4 + 0] * inv, accO[dt][rg * 4 + 1] * inv);
            val.y = pk2(accO[dt][rg * 4 + 2] * inv, accO[dt][rg * 4 + 3] * inv);
            *(uint2*)((char*)attnF + ((size_t)rowblk * 4096 + g * 32 + l31) * 16 + hi * 8) = val;
        }
}

// ---------------- out projection v3: fragment-major, split MFMA chains ----------------
__global__ __launch_bounds__(256, 2) void k_out(
    const unsigned short* __restrict__ attnF, const unsigned short* __restrict__ woF,
    const float* __restrict__ bias, float* __restrict__ out) {
    int wave = threadIdx.x >> 6, lane = threadIdx.x & 63;
    int l31 = lane & 31, hi = lane >> 5;
    int W = blockIdx.x * 4 + wave;   // 0..1535
    int nb = W / 6, cb = W % 6;      // 256 n-blocks x 6 c-blocks
    const unsigned short* A = attnF + (size_t)nb * 4096 * 8;
    const unsigned short* B = woF + (size_t)cb * 4096 * 8;

    f32x16 acc0, acc1;
    #pragma unroll
    for (int r = 0; r < 16; r++) { acc0[r] = 0.f; acc1[r] = 0.f; }
    #pragma unroll 8
    for (int kc = 0; kc < 32; kc++) {
        bf16x8 a0 = *(const bf16x8*)(A + (((2 * kc) * 2 + hi) * 32 + l31) * 8);
        bf16x8 b0 = *(const bf16x8*)(B + (((2 * kc) * 2 + hi) * 32 + l31) * 8);
        bf16x8 a1 = *(const bf16x8*)(A + (((2 * kc + 1) * 2 + hi) * 32 + l31) * 8);
        bf16x8 b1 = *(const bf16x8*)(B + (((2 * kc + 1) * 2 + hi) * 32 + l31) * 8);
        acc0 = __builtin_amdgcn_mfma_f32_32x32x16_bf16(a0, b0, acc0, 0, 0, 0);
        acc1 = __builtin_amdgcn_mfma_f32_32x32x16_bf16(a1, b1, acc1, 0, 0, 0);
    }
    float bi = bias[cb * 32 + l31];
    #pragma unroll
    for (int r = 0; r < 16; r++) {
        int n = nb * 32 + (r & 3) + 8 * (r >> 2) + 4 * hi;
        out[(size_t)n * DIM + cb * 32 + l31] = acc0[r] + acc1[r] + bi;
    }
}

extern "C" void kernel_launch(void* const* d_in, const int* in_sizes, int n_in,
                              void* d_out, int out_size, void* d_ws, size_t ws_size,
                              hipStream_t stream) {
    const float* x     = (const float*)d_in[0];
    const float* shift = (const float*)d_in[1];
    const float* scale = (const float*)d_in[2];
    const float* nw    = (const float*)d_in[3];
    const float* nbv   = (const float*)d_in[4];
    const float* wqkv  = (const float*)d_in[5];
    const float* wout  = (const float*)d_in[6];
    const float* bout  = (const float*)d_in[7];
    float* out = (float*)d_out;

    char* ws = (char*)d_ws;
    unsigned short* hF    = (unsigned short*)(ws + 0);
    unsigned short* wF    = (unsigned short*)(ws + 3145728);
    unsigned short* woF   = (unsigned short*)(ws + 3145728 + 1179648);
    unsigned short* qmF   = (unsigned short*)(ws + 4718592);
    unsigned short* kmF   = (unsigned short*)(ws + 4718592 + 16777216);
    unsigned short* vtF   = (unsigned short*)(ws + 4718592 + 2 * 16777216);
    unsigned short* attnF = (unsigned short*)(ws + 4718592 + 3 * 16777216);

    k_pre<<<dim3(5120), dim3(256), 0, stream>>>(x, shift, scale, nw, nbv, wqkv, wout, hF, wF, woF);
    k_qkv<<<dim3(48, 64), dim3(256), 0, stream>>>(hF, wF, qmF, kmF, vtF);
    k_attn<<<dim3(128, 8), dim3(256), 0, stream>>>(qmF, kmF, vtF, attnF);
    k_out<<<dim3(384), dim3(256), 0, stream>>>(attnF, woF, bout, out);
}